// Round 3
// baseline (112120.911 us; speedup 1.0000x reference)
//
#include <hip/hip_runtime.h>
#include <hip/hip_bf16.h>

// ---------------------------------------------------------------------------
// BayesianFilter: graph-GRU recurrent net.
// Key trick: gconv(xe_t) is linear in x_t, so edge aggregation is done ONCE in
// C-space (16 dims) for all t (k_agg), and the fused weight W_eg = W_enc@W_gX
// turns the per-step gconv into a row-local 16->64 matmul. After that the
// whole recurrence is row-parallel: one persistent kernel, no grid syncs.
//
// Round 3: round-2 counters showed 97 GB of TCC traffic from k_mega with only
// VGPR=128 -> local float[4] arrays (passed as decayed pointers to helpers)
// were demoted to scratch; every accumulate was a private-memory RMW. This
// version has ZERO address-taken locals in k_mega: all state is struct v4
// (named scalars), helpers return by value, accumulates are macros.
// ---------------------------------------------------------------------------

typedef unsigned short u16;

constexpr int N_ = 8, V_ = 2048, C_ = 16, T_ = 150, L_ = 64, E_ = 32768;
constexpr int NV_ = N_ * V_;             // 16384 rows
constexpr int CT_ = C_ * T_;             // 2400

// ---- workspace layout (bytes) ----
constexpr size_t SZ_AGGT   = (size_t)T_ * N_ * V_ * C_ * 2;     // 78,643,200 bf16
constexpr size_t OFF_AGGT  = 0;
constexpr size_t OFF_COUNTS= OFF_AGGT + SZ_AGGT;                // int[V]
constexpr size_t OFF_S     = OFF_COUNTS + 8192;                 // float[V]
constexpr size_t OFF_RP    = OFF_S + 8192;                      // int[V+1] (pad)
constexpr size_t OFF_CUR   = OFF_RP + 8448;                     // int[V]
constexpr size_t OFF_CSRC  = OFF_CUR + 8192;                    // int[E]
constexpr size_t OFF_CATT  = OFF_CSRC + 131072;                 // float[E]
constexpr size_t OFF_WEGA  = OFF_CATT + 131072;                 // bf16[16][64]
constexpr size_t OFF_WEGB  = OFF_WEGA + 2048;
constexpr size_t OFF_BEGA  = OFF_WEGB + 2048;                   // float[64]
constexpr size_t OFF_BEGB  = OFF_BEGA + 256;
constexpr size_t OFF_FLAG  = OFF_BEGB + 256;                    // int dtype flag
constexpr size_t OFF_STAGE = OFF_FLAG + 256;                    // bf16 [T][NV][C]
constexpr size_t NEED_STAGE= OFF_STAGE + SZ_AGGT;               // ~157.6 MB

// ---- mega-kernel LDS layout (bytes). pitches chosen for <=2-way banks ----
constexpr int PITCH = 68;   // ushorts; row stride 136B -> bank stride 34 -> 2-way
constexpr int PEG   = 20;   // ushorts; 40B -> 10 dwords -> 2-way
constexpr int L_WIT = 0;                  // [192][68] bf16 = 26112
constexpr int L_WHT = 26112;              // 26112
constexpr int L_W1H = 52224;              // [64][68]  = 8704
constexpr int L_W2  = 60928;              // 8704
constexpr int L_WDEC= 69632;              // [16][68]  = 2176
constexpr int L_WEG = 71808;              // [64][20]  = 2560
constexpr int L_FB  = 74368;              // float[336] (pad 1408)
constexpr int L_H   = 75776;              // bf16[16][64] = 2048
constexpr int L_M   = 77824;              // 2048
constexpr int L_AGG = 79872;              // bf16[16][16] = 512
constexpr int L_S   = 80384;              // float[16]
constexpr int LDS_MEGA = 80448;           // <= 81920 -> 2 blocks/CU

#define DEVI __device__ __forceinline__

DEVI float bf2f(u16 u) {
    unsigned int v = ((unsigned int)u) << 16;
    float f; __builtin_memcpy(&f, &v, 4); return f;
}
DEVI u16 f2bf(float f) {   // round-to-nearest-even
    unsigned int v; __builtin_memcpy(&v, &f, 4);
    unsigned int r = (v + 0x7fffu + ((v >> 16) & 1u)) >> 16;
    return (u16)r;
}
// dtype-flag-aware scalar load: element i of a float32 OR bf16 buffer
DEVI float ldf(const void* p, size_t i, int f32) {
    return f32 ? ((const float*)p)[i] : bf2f(((const u16*)p)[i]);
}
DEVI float sigm(float v) { return 1.f / (1.f + __expf(-v)); }
DEVI float tanh_(float v) {   // overflow-safe tanh via exp of -2|x|
    float a = fabsf(v);
    float e = __expf(-2.f * a);
    float t = (1.f - e) / (1.f + e);
    return v < 0.f ? -t : t;
}

// ---- scalar-struct vec4: never address-taken, always register-resident ----
struct v4 { float x, y, z, w; };
struct Gru4 { v4 az, ar, ani, anh; };

DEVI v4 mkv4(float a) { v4 r; r.x = a; r.y = a; r.z = a; r.w = a; return r; }
DEVI v4 ld4(const u16* p) {
    ushort4 u = *reinterpret_cast<const ushort4*>(p);
    v4 r; r.x = bf2f(u.x); r.y = bf2f(u.y); r.z = bf2f(u.z); r.w = bf2f(u.w);
    return r;
}
DEVI float hsum(v4 a) { return (a.x + a.y) + (a.z + a.w); }
#define FMA4(ACC, A, B) do { v4 _a = (A), _b = (B); \
    (ACC).x += _a.x * _b.x; (ACC).y += _a.y * _b.y; \
    (ACC).z += _a.z * _b.z; (ACC).w += _a.w * _b.w; } while (0)

// transposed weight loads into LDS: dst[o*pitch + k] = src[k*O + o]
DEVI void loadT64(u16* dst, const void* src, int O, int pitch, int f32) {
    for (int i = threadIdx.x; i < 64 * O; i += 256) {
        int o = i >> 6, k = i & 63;
        dst[o * pitch + k] = f2bf(ldf(src, (size_t)k * O + o, f32));
    }
}
DEVI void loadT16(u16* dst, const void* src, int O, int pitch, int f32) {
    for (int i = threadIdx.x; i < 16 * O; i += 256) {
        int o = i >> 4, k = i & 15;
        dst[o * pitch + k] = f2bf(ldf(src, (size_t)k * O + o, f32));
    }
}
DEVI void loadBias(float* dst, const void* src, int n, int f32) {
    for (int i = threadIdx.x; i < n; i += 256) dst[i] = ldf(src, i, f32);
}

// out[16 x 64] = act[16 x 64] @ W[64 x 64] + init  (WT layout [o][k])
// thread (l, rb) computes rows rb, rb+4, rb+8, rb+12 of column l.
DEVI v4 gemm64(const u16* WT, const u16* act, int l, int rb, v4 init) {
    const u16* w  = WT + l * PITCH;
    const u16* a0 = act + (rb +  0) * 64;
    const u16* a1 = act + (rb +  4) * 64;
    const u16* a2 = act + (rb +  8) * 64;
    const u16* a3 = act + (rb + 12) * 64;
    v4 c0 = mkv4(0.f), c1 = mkv4(0.f), c2 = mkv4(0.f), c3 = mkv4(0.f);
#pragma unroll
    for (int k4 = 0; k4 < 16; ++k4) {
        v4 wv = ld4(w + 4 * k4);
        FMA4(c0, ld4(a0 + 4 * k4), wv);
        FMA4(c1, ld4(a1 + 4 * k4), wv);
        FMA4(c2, ld4(a2 + 4 * k4), wv);
        FMA4(c3, ld4(a3 + 4 * k4), wv);
    }
    v4 r;
    r.x = init.x + hsum(c0); r.y = init.y + hsum(c1);
    r.z = init.z + hsum(c2); r.w = init.w + hsum(c3);
    return r;
}

// fused GRU gate GEMMs: az = (m@Wi_z + h@Wh_z + b_z), ar likewise,
// ani = m@Wi_n + b_n, anh = h@Wh_n. Components .x/.y/.z/.w = rows rb+0/4/8/12.
DEVI Gru4 gruGemm(const u16* WiT, const u16* WhT, const u16* mS, const u16* hS,
                  int l, int rb, const float* bg) {
    const u16* wz = WiT + (  0 + l) * PITCH;
    const u16* wr = WiT + ( 64 + l) * PITCH;
    const u16* wn = WiT + (128 + l) * PITCH;
    const u16* vz = WhT + (  0 + l) * PITCH;
    const u16* vr = WhT + ( 64 + l) * PITCH;
    const u16* vn = WhT + (128 + l) * PITCH;
    const u16* m0 = mS + (rb +  0) * 64;
    const u16* m1 = mS + (rb +  4) * 64;
    const u16* m2 = mS + (rb +  8) * 64;
    const u16* m3 = mS + (rb + 12) * 64;
    const u16* h0 = hS + (rb +  0) * 64;
    const u16* h1 = hS + (rb +  4) * 64;
    const u16* h2 = hS + (rb +  8) * 64;
    const u16* h3 = hS + (rb + 12) * 64;
    v4 z0 = mkv4(0.f), z1 = z0, z2 = z0, z3 = z0;
    v4 r0 = z0, r1 = z0, r2 = z0, r3 = z0;
    v4 i0 = z0, i1 = z0, i2 = z0, i3 = z0;
    v4 n0 = z0, n1 = z0, n2 = z0, n3 = z0;
#pragma unroll
    for (int k4 = 0; k4 < 16; ++k4) {
        v4 wa = ld4(wz + 4*k4), wb = ld4(wr + 4*k4), wc = ld4(wn + 4*k4);
        v4 wd = ld4(vz + 4*k4), we = ld4(vr + 4*k4), wf = ld4(vn + 4*k4);
#define GRU_ROW(MP, HP, AZ, AR, ANI, ANH) do { \
        v4 mm = ld4(MP + 4*k4), hh = ld4(HP + 4*k4); \
        FMA4(AZ, mm, wa);  FMA4(AZ, hh, wd); \
        FMA4(AR, mm, wb);  FMA4(AR, hh, we); \
        FMA4(ANI, mm, wc); FMA4(ANH, hh, wf); } while (0)
        GRU_ROW(m0, h0, z0, r0, i0, n0);
        GRU_ROW(m1, h1, z1, r1, i1, n1);
        GRU_ROW(m2, h2, z2, r2, i2, n2);
        GRU_ROW(m3, h3, z3, r3, i3, n3);
#undef GRU_ROW
    }
    Gru4 g;
    float bz = bg[l], br = bg[64 + l], bn = bg[128 + l];
    g.az.x  = bz + hsum(z0); g.az.y  = bz + hsum(z1);
    g.az.z  = bz + hsum(z2); g.az.w  = bz + hsum(z3);
    g.ar.x  = br + hsum(r0); g.ar.y  = br + hsum(r1);
    g.ar.z  = br + hsum(r2); g.ar.w  = br + hsum(r3);
    g.ani.x = bn + hsum(i0); g.ani.y = bn + hsum(i1);
    g.ani.z = bn + hsum(i2); g.ani.w = bn + hsum(i3);
    g.anh.x = hsum(n0); g.anh.y = hsum(n1);
    g.anh.z = hsum(n2); g.anh.w = hsum(n3);
    return g;
}

// m = agg_c @ W_eg + S * b_eg  -> mS (bf16)
DEVI void mcalc(const u16* WegT, const u16* aggS, const float* beg,
                const float* Sl, int l, int rb, u16* mS) {
    const u16* w = WegT + l * PEG;
    v4 w0 = ld4(w), w1 = ld4(w + 4), w2 = ld4(w + 8), w3 = ld4(w + 12);
    float bl = beg[l];
#define MROW(J) do { int r = rb + 4*(J); \
    v4 acc = mkv4(0.f); \
    FMA4(acc, ld4(aggS + r*16     ), w0); FMA4(acc, ld4(aggS + r*16 +  4), w1); \
    FMA4(acc, ld4(aggS + r*16 +  8), w2); FMA4(acc, ld4(aggS + r*16 + 12), w3); \
    mS[r * 64 + l] = f2bf(Sl[r] * bl + hsum(acc)); } while (0)
    MROW(0); MROW(1); MROW(2); MROW(3);
#undef MROW
}

// GRU nonlinearity for one row (all scalars)
#define GRU_OUT(AZ, AR, ANI, ANH, HOLD, HNEW) do { \
    float _z = sigm(AZ); float _r = sigm(AR); \
    float _n = tanh_((ANI) + _r * (ANH)); \
    HNEW = (1.f - _z) * _n + _z * (HOLD); } while (0)

DEVI void decodeStore(const u16* WdT, const u16* hS, const float* bd,
                      int rg, int cg, void* outp, int staged, int isf32,
                      int base, int t) {
    const u16* w = WdT + cg * PITCH;
    const u16* a = hS + rg * 64;
    v4 acc = mkv4(0.f);
#pragma unroll
    for (int k4 = 0; k4 < 16; ++k4) FMA4(acc, ld4(w + 4*k4), ld4(a + 4*k4));
    float r = bd[cg] + hsum(acc);
    if (staged) {
        ((u16*)outp)[((size_t)t * NV_ + base + rg) * C_ + cg] = f2bf(r);
    } else {
        size_t off = (size_t)(base + rg) * CT_ + (size_t)cg * T_ + t;
        if (isf32) ((float*)outp)[off] = r;
        else       ((u16*)outp)[off] = f2bf(r);
    }
}

// ---------------------------------------------------------------------------
// dtype detection: interpret first 1024 u16 of x as bf16. True bf16 N(0,1)
// data has exponent field <= ~0x81. f32 data misread as bf16 gives ~40% of
// the low-half u16s an exponent >= 0x9A (|v| >= 2^27). Count >= 8 -> f32.
// ---------------------------------------------------------------------------
__global__ void k_detect(const u16* __restrict__ x, int* __restrict__ flag) {
    __shared__ int cnt;
    if (threadIdx.x == 0) cnt = 0;
    __syncthreads();
    int local = 0;
#pragma unroll
    for (int j = 0; j < 4; ++j) {
        u16 u = x[threadIdx.x * 4 + j];
        int ex = (u >> 7) & 0xFF;
        if (ex >= 0x9A) ++local;
    }
    if (local) atomicAdd(&cnt, local);
    __syncthreads();
    if (threadIdx.x == 0) *flag = (cnt >= 8) ? 1 : 0;
}

// ---------------------------------------------------------------------------
// CSR build
// ---------------------------------------------------------------------------
__global__ void k_count(const int* __restrict__ ei, const void* __restrict__ eattr,
                        const int* __restrict__ flag,
                        int* __restrict__ counts, float* __restrict__ S) {
    int f32 = *flag;
    int e = blockIdx.x * 256 + threadIdx.x;
    if (e < E_) {
        int dst = ei[E_ + e];
        atomicAdd(&counts[dst], 1);
        atomicAdd(&S[dst], ldf(eattr, e, f32));
    }
}

__global__ void k_scan(const int* __restrict__ counts, int* __restrict__ row_ptr,
                       int* __restrict__ cursor) {
    __shared__ int lds[256];
    int tid = threadIdx.x;
    int base = tid * 8, s = 0;
    int l0, l1, l2, l3, l4, l5, l6, l7;
    l0 = s; s += counts[base + 0]; l1 = s; s += counts[base + 1];
    l2 = s; s += counts[base + 2]; l3 = s; s += counts[base + 3];
    l4 = s; s += counts[base + 4]; l5 = s; s += counts[base + 5];
    l6 = s; s += counts[base + 6]; l7 = s; s += counts[base + 7];
    lds[tid] = s; __syncthreads();
    for (int d = 1; d < 256; d <<= 1) {
        int v = (tid >= d) ? lds[tid - d] : 0;
        __syncthreads();
        lds[tid] += v;
        __syncthreads();
    }
    int off = (tid == 0) ? 0 : lds[tid - 1];
    row_ptr[base + 0] = off + l0; cursor[base + 0] = off + l0;
    row_ptr[base + 1] = off + l1; cursor[base + 1] = off + l1;
    row_ptr[base + 2] = off + l2; cursor[base + 2] = off + l2;
    row_ptr[base + 3] = off + l3; cursor[base + 3] = off + l3;
    row_ptr[base + 4] = off + l4; cursor[base + 4] = off + l4;
    row_ptr[base + 5] = off + l5; cursor[base + 5] = off + l5;
    row_ptr[base + 6] = off + l6; cursor[base + 6] = off + l6;
    row_ptr[base + 7] = off + l7; cursor[base + 7] = off + l7;
    if (tid == 255) row_ptr[V_] = lds[255];
}

__global__ void k_fill(const int* __restrict__ ei, const void* __restrict__ eattr,
                       const int* __restrict__ flag,
                       int* __restrict__ cursor, int* __restrict__ col_src,
                       float* __restrict__ col_att) {
    int f32 = *flag;
    int e = blockIdx.x * 256 + threadIdx.x;
    if (e < E_) {
        int dst = ei[E_ + e];
        int pos = atomicAdd(&cursor[dst], 1);
        col_src[pos] = ei[e];
        col_att[pos] = ldf(eattr, e, f32);
    }
}

// fused weights: W_egX = W_enc @ W_gX ; b_egX = b_enc @ W_gX
__global__ void k_wprep(const void* __restrict__ W_enc, const void* __restrict__ b_enc,
                        const void* __restrict__ W_gd, const void* __restrict__ W_gc,
                        const int* __restrict__ flag,
                        u16* __restrict__ wegA, u16* __restrict__ wegB,
                        float* __restrict__ begA, float* __restrict__ begB) {
    int f32 = *flag;
    int tid = threadIdx.x;
    for (int idx = tid; idx < 1024; idx += 256) {
        int c = idx >> 6, l = idx & 63;
        float sa = 0.f, sb = 0.f;
        for (int k = 0; k < 64; ++k) {
            float we = ldf(W_enc, c * 64 + k, f32);
            sa += we * ldf(W_gd, k * 64 + l, f32);
            sb += we * ldf(W_gc, k * 64 + l, f32);
        }
        wegA[idx] = f2bf(sa); wegB[idx] = f2bf(sb);
    }
    if (tid < 64) {
        float sa = 0.f, sb = 0.f;
        for (int k = 0; k < 64; ++k) {
            float be = ldf(b_enc, k, f32);
            sa += be * ldf(W_gd, k * 64 + tid, f32);
            sb += be * ldf(W_gc, k * 64 + tid, f32);
        }
        begA[tid] = sa; begB[tid] = sb;
    }
}

// ---------------------------------------------------------------------------
// pre-aggregation: aggT[t][n][v][c] = sum_{e: dst=v} attr_e * x[n, src_e, c, t]
// block = (n, 4 dst nodes); x rows are contiguous (c,t) slabs -> coalesced.
// ---------------------------------------------------------------------------
__global__ __launch_bounds__(256) void k_agg(
    const void* __restrict__ x, const int* __restrict__ flag,
    const int* __restrict__ row_ptr,
    const int* __restrict__ col_src, const float* __restrict__ col_att,
    u16* __restrict__ aggT) {
    __shared__ float lbuf[4 * CT_];   // 38,400 B
    int f32 = *flag;
    int tid = threadIdx.x;
    int n  = blockIdx.x >> 9;
    int v0 = (blockIdx.x & 511) * 4;
    for (int d = 0; d < 4; ++d) {
        int v = v0 + d;
        int e0 = row_ptr[v], e1 = row_ptr[v + 1];
        float acc[10];
#pragma unroll
        for (int k = 0; k < 10; ++k) acc[k] = 0.f;
        for (int e = e0; e < e1; ++e) {
            float a = col_att[e];
            size_t ro = (size_t)(n * V_ + col_src[e]) * CT_;
            if (f32) {
                const float* xr = (const float*)x + ro;
#pragma unroll
                for (int k = 0; k < 10; ++k) {
                    int idx = tid + 256 * k;
                    if (idx < CT_) acc[k] += a * xr[idx];
                }
            } else {
                const u16* xr = (const u16*)x + ro;
#pragma unroll
                for (int k = 0; k < 10; ++k) {
                    int idx = tid + 256 * k;
                    if (idx < CT_) acc[k] += a * bf2f(xr[idx]);
                }
            }
        }
#pragma unroll
        for (int k = 0; k < 10; ++k) {
            int idx = tid + 256 * k;
            if (idx < CT_) lbuf[d * CT_ + idx] = acc[k];
        }
    }
    __syncthreads();
    // write in [t][n][v][c] order (128B contiguous per t)
    for (int w = tid; w < 4 * CT_; w += 256) {
        int t = w >> 6, rem = w & 63, d = rem >> 4, c = rem & 15;
        aggT[((size_t)(t * N_ + n) * V_ + v0 + d) * C_ + c] =
            f2bf(lbuf[d * CT_ + c * T_ + t]);
    }
}

// ---------------------------------------------------------------------------
// mega kernel: phase A (domain GRU, 150 steps) -> dom MLP + zdterm ->
// phase B (ODE + GRU + decode, steps 1..149). 16 rows / block, all row-local.
// thread maps: (l = tid&63, rows rb+4j) for GEMMs; (rg = tid>>4, cg = tid&15)
// for agg/x0/decode. NO local arrays anywhere (scratch demotion, round 2).
// ---------------------------------------------------------------------------
__global__ __launch_bounds__(256, 2) void k_mega(
    const void* __restrict__ x, const u16* __restrict__ aggT,
    const float* __restrict__ Sg, const int* __restrict__ flag,
    const void* __restrict__ W_enc, const void* __restrict__ b_enc,
    const void* __restrict__ gd_Wi, const void* __restrict__ gd_Wh, const void* __restrict__ gd_b,
    const void* __restrict__ W_dom1, const void* __restrict__ b_dom1,
    const void* __restrict__ W_dom2, const void* __restrict__ b_dom2,
    const void* __restrict__ ode_W1, const void* __restrict__ ode_b1,
    const void* __restrict__ ode_W2, const void* __restrict__ ode_b2,
    const void* __restrict__ gc_Wi, const void* __restrict__ gc_Wh, const void* __restrict__ gc_b,
    const void* __restrict__ W_dec, const void* __restrict__ b_dec,
    const u16* __restrict__ wegA, const u16* __restrict__ wegB,
    const float* __restrict__ begA, const float* __restrict__ begB,
    void* __restrict__ outp, int staged) {
    extern __shared__ char smem[];
    u16* WiT  = (u16*)(smem + L_WIT);
    u16* WhT  = (u16*)(smem + L_WHT);
    u16* W1hT = (u16*)(smem + L_W1H);
    u16* W2T  = (u16*)(smem + L_W2);
    u16* WdT  = (u16*)(smem + L_WDEC);
    u16* WegT = (u16*)(smem + L_WEG);
    float* fB = (float*)(smem + L_FB);    // [0..191] gate bias, [192..255] b_eg,
                                          // [256..319] ode_b2, [320..335] b_dec
    u16* hS   = (u16*)(smem + L_H);
    u16* mS   = (u16*)(smem + L_M);
    u16* aggS = (u16*)(smem + L_AGG);
    float* Sl = (float*)(smem + L_S);

    const int f32 = *flag;
    const int tid = threadIdx.x;
    const int l = tid & 63, rb = tid >> 6;
    const int rg = tid >> 4, cg = tid & 15;
    const int base = blockIdx.x * 16;
    const int n = base >> 11, v0 = base & 2047;

#define STAGE_H(DST, V) do { \
    DST[(rb +  0) * 64 + l] = f2bf((V).x); \
    DST[(rb +  4) * 64 + l] = f2bf((V).y); \
    DST[(rb +  8) * 64 + l] = f2bf((V).z); \
    DST[(rb + 12) * 64 + l] = f2bf((V).w); } while (0)
#define STAGE_TANH(DST, V) do { \
    DST[(rb +  0) * 64 + l] = f2bf(tanh_((V).x)); \
    DST[(rb +  4) * 64 + l] = f2bf(tanh_((V).y)); \
    DST[(rb +  8) * 64 + l] = f2bf(tanh_((V).z)); \
    DST[(rb + 12) * 64 + l] = f2bf(tanh_((V).w)); } while (0)

    // ---- phase A setup
    loadT64(WiT, gd_Wi, 192, PITCH, f32);
    loadT64(WhT, gd_Wh, 192, PITCH, f32);
    for (int i = tid; i < 16 * 64; i += 256) {     // wegA already bf16
        int o = i >> 4, k = i & 15;
        WegT[o * PEG + k] = wegA[k * 64 + o];
    }
    loadBias(fB, gd_b, 192, f32);
    for (int i = tid; i < 64; i += 256) fB[192 + i] = begA[i];
    if (tid < 16) Sl[tid] = Sg[v0 + tid];
    __syncthreads();

    v4 hd = mkv4(0.f);
    for (int t = 0; t < T_; ++t) {
        aggS[tid] = aggT[((size_t)(t * N_ + n) * V_ + v0) * C_ + tid];
        STAGE_H(hS, hd);
        __syncthreads();
        mcalc(WegT, aggS, fB + 192, Sl, l, rb, mS);
        __syncthreads();
        Gru4 g = gruGemm(WiT, WhT, mS, hS, l, rb, fB);
        GRU_OUT(g.az.x, g.ar.x, g.ani.x, g.anh.x, hd.x, hd.x);
        GRU_OUT(g.az.y, g.ar.y, g.ani.y, g.anh.y, hd.y, hd.y);
        GRU_OUT(g.az.z, g.ar.z, g.ani.z, g.anh.z, hd.z, hd.z);
        GRU_OUT(g.az.w, g.ar.w, g.ani.w, g.anh.w, hd.w, hd.w);
        __syncthreads();
    }

    // ---- domain MLP: z_D = tanh(hd@Wdom1+b1)@Wdom2+b2 ; zt = zD@W1[64:]+ode_b1
    STAGE_H(hS, hd);
    loadT64(W1hT, W_dom1, 64, PITCH, f32);
    loadT64(W2T,  W_dom2, 64, PITCH, f32);
    loadT64(WiT,  (const void*)((const char*)ode_W1 + (size_t)64 * 64 * (f32 ? 4 : 2)),
            64, PITCH, f32);   // zD half of ode_W1
    loadBias(fB,       b_dom1, 64, f32);
    loadBias(fB + 64,  b_dom2, 64, f32);
    loadBias(fB + 128, ode_b1, 64, f32);
    __syncthreads();
    v4 t1 = gemm64(W1hT, hS, l, rb, mkv4(fB[l]));
    STAGE_TANH(mS, t1);
    __syncthreads();
    v4 zD = gemm64(W2T, mS, l, rb, mkv4(fB[64 + l]));
    __syncthreads();
    STAGE_H(hS, zD);
    __syncthreads();
    v4 zt = gemm64(WiT, hS, l, rb, mkv4(fB[128 + l]));
    __syncthreads();

    // ---- phase B setup
    loadT64(WiT, gc_Wi, 192, PITCH, f32);
    loadT64(WhT, gc_Wh, 192, PITCH, f32);
    loadT64(W1hT, ode_W1, 64, PITCH, f32);   // h half
    loadT64(W2T,  ode_W2, 64, PITCH, f32);
    loadT64(WdT,  W_dec, 16, PITCH, f32);
    loadT16(WegT, W_enc, 64, PEG, f32);      // raw W_enc for h0
    loadBias(fB, b_enc, 64, f32);
    loadBias(fB + 256, ode_b2, 64, f32);
    loadBias(fB + 320, b_dec, 16, f32);
    for (int i = tid; i < 64; i += 256) fB[192 + i] = begB[i];
    __syncthreads();
    // h0 = x[:,:,:,0] @ W_enc + b_enc
    aggS[tid] = f2bf(ldf(x, (size_t)(base + rg) * CT_ + (size_t)cg * T_, f32));
    __syncthreads();
    v4 h;
    {
        const u16* w = WegT + l * PEG;
        v4 w0 = ld4(w), w1 = ld4(w + 4), w2 = ld4(w + 8), w3 = ld4(w + 12);
        float bl = fB[l];
#define H0ROW(J, OUT) do { int r = rb + 4*(J); \
        v4 acc = mkv4(0.f); \
        FMA4(acc, ld4(aggS + r*16     ), w0); FMA4(acc, ld4(aggS + r*16 +  4), w1); \
        FMA4(acc, ld4(aggS + r*16 +  8), w2); FMA4(acc, ld4(aggS + r*16 + 12), w3); \
        OUT = bl + hsum(acc); hS[r * 64 + l] = f2bf(OUT); } while (0)
        H0ROW(0, h.x); H0ROW(1, h.y); H0ROW(2, h.z); H0ROW(3, h.w);
#undef H0ROW
    }
    __syncthreads();
    decodeStore(WdT, hS, fB + 320, rg, cg, outp, staged, f32, base, 0);
    for (int i = tid; i < 16 * 64; i += 256) {     // wegB already bf16
        int o = i >> 4, k = i & 15;
        WegT[o * PEG + k] = wegB[k * 64 + o];
    }
    loadBias(fB, gc_b, 192, f32);
    __syncthreads();

    for (int t = 1; t < T_; ++t) {
        // s1: agg load + ODE hidden u = tanh(h@W1h + zt)
        aggS[tid] = aggT[((size_t)(t * N_ + n) * V_ + v0) * C_ + tid];
        v4 u = gemm64(W1hT, hS, l, rb, zt);
        STAGE_TANH(mS, u);
        __syncthreads();
        // s2: dh = u@W2 + b2 ; h_ode = h + dh
        v4 dh = gemm64(W2T, mS, l, rb, mkv4(fB[256 + l]));
        v4 ho;
        ho.x = h.x + dh.x; ho.y = h.y + dh.y;
        ho.z = h.z + dh.z; ho.w = h.w + dh.w;
        __syncthreads();
        // s3: stage h_ode ; m = agg@W_eg + S*b_eg
        STAGE_H(hS, ho);
        mcalc(WegT, aggS, fB + 192, Sl, l, rb, mS);
        __syncthreads();
        // s4: GRU(m, h_ode)
        Gru4 g = gruGemm(WiT, WhT, mS, hS, l, rb, fB);
        GRU_OUT(g.az.x, g.ar.x, g.ani.x, g.anh.x, ho.x, h.x);
        GRU_OUT(g.az.y, g.ar.y, g.ani.y, g.anh.y, ho.y, h.y);
        GRU_OUT(g.az.z, g.ar.z, g.ani.z, g.anh.z, ho.z, h.z);
        GRU_OUT(g.az.w, g.ar.w, g.ani.w, g.anh.w, ho.w, h.w);
        __syncthreads();
        // s5: stage h_new, decode
        STAGE_H(hS, h);
        __syncthreads();
        decodeStore(WdT, hS, fB + 320, rg, cg, outp, staged, f32, base, t);
    }
#undef STAGE_H
#undef STAGE_TANH
}

// de-transpose staged output [t][row][c] -> d_out [row][c][t]
__global__ __launch_bounds__(256) void k_detrans(const u16* __restrict__ stage,
                                                 const int* __restrict__ flag,
                                                 void* __restrict__ out) {
    __shared__ u16 lt[8 * CT_];   // 38,400 B
    int f32 = *flag;
    int tid = threadIdx.x;
    int base = blockIdx.x * 8;
    int r = tid >> 4, c = tid & 15;
    for (int t = 0; t < T_; ++t) {
        if (tid < 128)
            lt[r * CT_ + c * T_ + t] = stage[((size_t)t * NV_ + base + r) * C_ + c];
    }
    __syncthreads();
    size_t ob = (size_t)base * CT_;
    if (f32) {
        float* o = (float*)out;
        for (int i = tid; i < 8 * CT_; i += 256) o[ob + i] = bf2f(lt[i]);
    } else {
        u16* o = (u16*)out;
        for (int i = tid; i < 8 * CT_; i += 256) o[ob + i] = lt[i];
    }
}

// ---------------------------------------------------------------------------
extern "C" void kernel_launch(void* const* d_in, const int* in_sizes, int n_in,
                              void* d_out, int out_size, void* d_ws, size_t ws_size,
                              hipStream_t stream) {
    const void* x      = d_in[0];
    const int*  ei     = (const int*)d_in[1];
    const void* eattr  = d_in[2];
    const void* W_enc  = d_in[3];
    const void* b_enc  = d_in[4];
    const void* W_gd   = d_in[5];
    const void* gd_Wi  = d_in[6];
    const void* gd_Wh  = d_in[7];
    const void* gd_b   = d_in[8];
    const void* W_dom1 = d_in[9];
    const void* b_dom1 = d_in[10];
    const void* W_dom2 = d_in[11];
    const void* b_dom2 = d_in[12];
    const void* ode_W1 = d_in[13];
    const void* ode_b1 = d_in[14];
    const void* ode_W2 = d_in[15];
    const void* ode_b2 = d_in[16];
    const void* W_gc   = d_in[17];
    const void* gc_Wi  = d_in[18];
    const void* gc_Wh  = d_in[19];
    const void* gc_b   = d_in[20];
    const void* W_dec  = d_in[21];
    const void* b_dec  = d_in[22];

    char* ws = (char*)d_ws;
    u16*   aggT    = (u16*)  (ws + OFF_AGGT);
    int*   counts  = (int*)  (ws + OFF_COUNTS);
    float* S       = (float*)(ws + OFF_S);
    int*   row_ptr = (int*)  (ws + OFF_RP);
    int*   cursor  = (int*)  (ws + OFF_CUR);
    int*   col_src = (int*)  (ws + OFF_CSRC);
    float* col_att = (float*)(ws + OFF_CATT);
    u16*   wegA    = (u16*)  (ws + OFF_WEGA);
    u16*   wegB    = (u16*)  (ws + OFF_WEGB);
    float* begA    = (float*)(ws + OFF_BEGA);
    float* begB    = (float*)(ws + OFF_BEGB);
    int*   flag    = (int*)  (ws + OFF_FLAG);
    u16*   stage   = (u16*)  (ws + OFF_STAGE);

    int staged = (ws_size >= NEED_STAGE) ? 1 : 0;
    void* mega_out = staged ? (void*)stage : d_out;

    // allow >64KB dynamic LDS (no-op where not required); idempotent per call
    (void)hipFuncSetAttribute((const void*)k_mega,
                              hipFuncAttributeMaxDynamicSharedMemorySize, LDS_MEGA);

    hipLaunchKernelGGL(k_detect, dim3(1), dim3(256), 0, stream, (const u16*)x, flag);
    hipMemsetAsync(ws + OFF_COUNTS, 0, 16384, stream);  // counts + S
    hipLaunchKernelGGL(k_count, dim3(E_ / 256), dim3(256), 0, stream,
                       ei, eattr, flag, counts, S);
    hipLaunchKernelGGL(k_scan, dim3(1), dim3(256), 0, stream,
                       counts, row_ptr, cursor);
    hipLaunchKernelGGL(k_fill, dim3(E_ / 256), dim3(256), 0, stream,
                       ei, eattr, flag, cursor, col_src, col_att);
    hipLaunchKernelGGL(k_wprep, dim3(1), dim3(256), 0, stream,
                       W_enc, b_enc, W_gd, W_gc, flag, wegA, wegB, begA, begB);
    hipLaunchKernelGGL(k_agg, dim3(N_ * V_ / 4), dim3(256), 0, stream,
                       x, flag, row_ptr, col_src, col_att, aggT);
    hipLaunchKernelGGL(k_mega, dim3(NV_ / 16), dim3(256), LDS_MEGA, stream,
                       x, aggT, S, flag, W_enc, b_enc, gd_Wi, gd_Wh, gd_b,
                       W_dom1, b_dom1, W_dom2, b_dom2,
                       ode_W1, ode_b1, ode_W2, ode_b2,
                       gc_Wi, gc_Wh, gc_b, W_dec, b_dec,
                       wegA, wegB, begA, begB, mega_out, staged);
    if (staged)
        hipLaunchKernelGGL(k_detrans, dim3(NV_ / 8), dim3(256), 0, stream,
                           stage, flag, d_out);
}